// Round 10
// baseline (135.563 us; speedup 1.0000x reference)
//
#include <hip/hip_runtime.h>
#include <math.h>

#define NFULL 4096   // DCT length per row
#define NH    2048   // half-size complex FFT
#define T     256    // threads per block (128 per row, 2 rows)

// float4-granular swizzle (pair-level). Element-level sw(i) = 2*swp(i>>1) | (i&1):
// preserves (even, even+1) adjacency => all paired accesses are one b128 op.
__device__ __forceinline__ int swp(int p) { return p ^ ((p >> 3) & 7); }
__device__ __forceinline__ int swe(int i) { return (swp(i >> 1) << 1) | (i & 1); }

__device__ __forceinline__ float2 cmul(float2 a, float2 b) {
    return make_float2(a.x * b.x - a.y * b.y, a.x * b.y + a.y * b.x);
}

__device__ __forceinline__ float2 sc(float ang) {
    float s, c;
    __sincosf(ang, &s, &c);
    return make_float2(c, s);
}

// 8-point DFT, no twiddles
__device__ __forceinline__ void dft8(float2 v[8]) {
    const float s = 0.70710678118654752f;
    float2 e0 = v[0], o0 = v[1], e1 = v[2], o1 = v[3];
    float2 e2 = v[4], o2 = v[5], e3 = v[6], o3 = v[7];
    float2 t0 = make_float2(e0.x + e2.x, e0.y + e2.y);
    float2 t1 = make_float2(e0.x - e2.x, e0.y - e2.y);
    float2 t2 = make_float2(e1.x + e3.x, e1.y + e3.y);
    float2 t3 = make_float2(e1.x - e3.x, e1.y - e3.y);
    float2 E0 = make_float2(t0.x + t2.x, t0.y + t2.y);
    float2 E2 = make_float2(t0.x - t2.x, t0.y - t2.y);
    float2 E1 = make_float2(t1.x + t3.y, t1.y - t3.x);
    float2 E3 = make_float2(t1.x - t3.y, t1.y + t3.x);
    float2 u0 = make_float2(o0.x + o2.x, o0.y + o2.y);
    float2 u1 = make_float2(o0.x - o2.x, o0.y - o2.y);
    float2 u2 = make_float2(o1.x + o3.x, o1.y + o3.y);
    float2 u3 = make_float2(o1.x - o3.x, o1.y - o3.y);
    float2 O0 = make_float2(u0.x + u2.x, u0.y + u2.y);
    float2 O2 = make_float2(u0.x - u2.x, u0.y - u2.y);
    float2 O1 = make_float2(u1.x + u3.y, u1.y - u3.x);
    float2 O3 = make_float2(u1.x - u3.y, u1.y + u3.x);
    O1 = make_float2(s * (O1.x + O1.y), s * (O1.y - O1.x));
    O2 = make_float2(O2.y, -O2.x);
    O3 = make_float2(s * (O3.y - O3.x), s * (-O3.x - O3.y));
    v[0] = make_float2(E0.x + O0.x, E0.y + O0.y);
    v[4] = make_float2(E0.x - O0.x, E0.y - O0.y);
    v[1] = make_float2(E1.x + O1.x, E1.y + O1.y);
    v[5] = make_float2(E1.x - O1.x, E1.y - O1.y);
    v[2] = make_float2(E2.x + O2.x, E2.y + O2.y);
    v[6] = make_float2(E2.x - O2.x, E2.y - O2.y);
    v[3] = make_float2(E3.x + O3.x, E3.y + O3.y);
    v[7] = make_float2(E3.x - O3.x, E3.y - O3.y);
}

__device__ __forceinline__ void dft4(float2 v[4]) {
    float2 t0 = make_float2(v[0].x + v[2].x, v[0].y + v[2].y);
    float2 t1 = make_float2(v[0].x - v[2].x, v[0].y - v[2].y);
    float2 t2 = make_float2(v[1].x + v[3].x, v[1].y + v[3].y);
    float2 t3 = make_float2(v[1].x - v[3].x, v[1].y - v[3].y);
    v[0] = make_float2(t0.x + t2.x, t0.y + t2.y);
    v[2] = make_float2(t0.x - t2.x, t0.y - t2.y);
    v[1] = make_float2(t1.x + t3.y, t1.y - t3.x);
    v[3] = make_float2(t1.x - t3.y, t1.y + t3.x);
}

// stage-1 inputs for butterfly q (Makhoul perm + real pack) from global
__device__ __forceinline__ void load_bfly(const float4* __restrict__ s4, int q, float2 v[8]) {
    float4 f0 = s4[q];
    float4 f1 = s4[q + 256];
    float4 f2 = s4[q + 512];
    float4 f3 = s4[q + 768];
    float4 g3 = s4[1023 - q];
    float4 g2 = s4[767 - q];
    float4 g1 = s4[511 - q];
    float4 g0 = s4[255 - q];
    v[0] = make_float2(f0.x, f0.z);
    v[1] = make_float2(f1.x, f1.z);
    v[2] = make_float2(f2.x, f2.z);
    v[3] = make_float2(f3.x, f3.z);
    v[4] = make_float2(g3.w, g3.y);
    v[5] = make_float2(g2.w, g2.y);
    v[6] = make_float2(g1.w, g1.y);
    v[7] = make_float2(g0.w, g0.y);
}

__device__ __forceinline__ void twiddle8(float2 v[8], float a) {
    float2 w1 = sc(a), w2 = sc(2.0f * a), w4 = sc(4.0f * a);
    float2 w3 = cmul(w1, w2), w5 = cmul(w1, w4), w6 = cmul(w2, w4);
    float2 w7 = cmul(w3, w4);
    v[1] = cmul(v[1], w1); v[2] = cmul(v[2], w2); v[3] = cmul(v[3], w3);
    v[4] = cmul(v[4], w4); v[5] = cmul(v[5], w5); v[6] = cmul(v[6], w6);
    v[7] = cmul(v[7], w7);
}

// DCT-II row pass: Makhoul perm + real-packed 2048-pt Stockham FFT (radix 8,8,8,4).
// PAIRED butterflies (q=2m, 2m+1 per thread) => ALL stage LDS traffic is b128.
// 2 rows per 256-thr block (threads 0-127 row A, 128-255 row B), single in-place
// 32KB LDS, 6 barriers.
__global__ __launch_bounds__(T, 4) void dct_rows_b128(const float* __restrict__ in,
                                                      const float* __restrict__ expk,
                                                      float* __restrict__ out) {
    __shared__ float4 L4[2][NH / 2];   // 2 x 16 KB
    const int h = threadIdx.x >> 7;    // row within block
    const int m = threadIdx.x & 127;   // pair index 0..127
    const int row = 2 * blockIdx.x + h;
    float4* __restrict__ A4 = L4[h];
    float2* __restrict__ A2 = (float2*)A4;
    const float4* __restrict__ src4 = (const float4*)(in + (size_t)row * NFULL);

    float2 va[8], vb[8];
    // ---- stage 1: R=8, Ns=1, global -> LDS. butterflies 2m, 2m+1 write elements
    // 16m..16m+15 (8 consecutive float4s) ----
    load_bfly(src4, 2 * m, va);
    load_bfly(src4, 2 * m + 1, vb);
    dft8(va);
    dft8(vb);
    #pragma unroll
    for (int j = 0; j < 4; ++j)
        A4[swp(8 * m + j)] = make_float4(va[2 * j].x, va[2 * j].y, va[2 * j + 1].x, va[2 * j + 1].y);
    #pragma unroll
    for (int j = 0; j < 4; ++j)
        A4[swp(8 * m + 4 + j)] = make_float4(vb[2 * j].x, vb[2 * j].y, vb[2 * j + 1].x, vb[2 * j + 1].y);
    __syncthreads();

    // ---- stage 2: R=8, Ns=8. read pairs (2m,2m+1)+256r ----
    {
        #pragma unroll
        for (int r = 0; r < 8; ++r) {
            float4 f = A4[swp(m + 128 * r)];
            va[r] = make_float2(f.x, f.y);
            vb[r] = make_float2(f.z, f.w);
        }
        __syncthreads();
        const float a0 = -(float)M_PI / 32.0f * (float)((2 * m) & 7);
        twiddle8(va, a0);
        twiddle8(vb, a0 - (float)M_PI / 32.0f);
        dft8(va);
        dft8(vb);
        const int d0 = (((2 * m) >> 3) << 6) + ((2 * m) & 7);   // even; pair (d0+8r, d0+1+8r)
        #pragma unroll
        for (int r = 0; r < 8; ++r)
            A4[swp((d0 + 8 * r) >> 1)] = make_float4(va[r].x, va[r].y, vb[r].x, vb[r].y);
    }
    __syncthreads();

    // ---- stage 3: R=8, Ns=64 ----
    {
        #pragma unroll
        for (int r = 0; r < 8; ++r) {
            float4 f = A4[swp(m + 128 * r)];
            va[r] = make_float2(f.x, f.y);
            vb[r] = make_float2(f.z, f.w);
        }
        __syncthreads();
        const float a0 = -(float)M_PI / 256.0f * (float)((2 * m) & 63);
        twiddle8(va, a0);
        twiddle8(vb, a0 - (float)M_PI / 256.0f);
        dft8(va);
        dft8(vb);
        const int d0 = (((2 * m) >> 6) << 9) + ((2 * m) & 63);
        #pragma unroll
        for (int r = 0; r < 8; ++r)
            A4[swp((d0 + 64 * r) >> 1)] = make_float4(va[r].x, va[r].y, vb[r].x, vb[r].y);
    }
    __syncthreads();

    // ---- stage 4: R=4, Ns=512; butterflies (2p, 2p+1) for p in {m, m+128};
    // reads/writes the SAME slots -> thread-local in-place, no internal barrier ----
    #pragma unroll
    for (int g = 0; g < 2; ++g) {
        const int p = m + 128 * g;
        float2 ua[4], ub[4];
        #pragma unroll
        for (int r = 0; r < 4; ++r) {
            float4 f = A4[swp(p + 256 * r)];
            ua[r] = make_float2(f.x, f.y);
            ub[r] = make_float2(f.z, f.w);
        }
        const float a0 = -(float)M_PI / 1024.0f * (float)(2 * p);
        {
            float2 w1 = sc(a0), w2 = sc(2.0f * a0);
            float2 w3 = cmul(w1, w2);
            ua[1] = cmul(ua[1], w1); ua[2] = cmul(ua[2], w2); ua[3] = cmul(ua[3], w3);
        }
        {
            const float a1 = a0 - (float)M_PI / 1024.0f;
            float2 w1 = sc(a1), w2 = sc(2.0f * a1);
            float2 w3 = cmul(w1, w2);
            ub[1] = cmul(ub[1], w1); ub[2] = cmul(ub[2], w2); ub[3] = cmul(ub[3], w3);
        }
        dft4(ua);
        dft4(ub);
        #pragma unroll
        for (int r = 0; r < 4; ++r)
            A4[swp(p + 256 * r)] = make_float4(ua[r].x, ua[r].y, ub[r].x, ub[r].y);
    }
    __syncthreads();

    // ---- epilogue: rfft untangle + DCT twiddle; pairs k0=2m+256i, k1=k0+1 ----
    const float2* __restrict__ ek = (const float2*)expk;
    float* __restrict__ dst = out + (size_t)row * NFULL;
    #pragma unroll
    for (int i = 0; i < 8; ++i) {
        const int k0 = 2 * m + 256 * i;
        float4 Z = A4[swp(m + 128 * i)];         // elements k0, k0+1
        float2 Zk0 = make_float2(Z.x, Z.y);
        float2 Zk1 = make_float2(Z.z, Z.w);
        // element k1 (always regular since k1 is odd)
        const int k1 = k0 + 1;
        float2 Zr1 = A2[swe(NH - k1)];
        float2 E1 = make_float2(0.5f * (Zk1.x + Zr1.x), 0.5f * (Zk1.y - Zr1.y));
        float2 O1 = make_float2(0.5f * (Zk1.y + Zr1.y), 0.5f * (Zr1.x - Zk1.x));
        float2 uu1 = sc(-(float)M_PI / 2048.0f * (float)k1);
        float2 Y1 = make_float2(E1.x + uu1.x * O1.x - uu1.y * O1.y,
                                E1.y + uu1.x * O1.y + uu1.y * O1.x);
        float2 wk1 = ek[k1];
        float2 wn1 = ek[NFULL - k1];
        float r1  = wk1.x * Y1.x - wk1.y * Y1.y;
        float rm1 = wn1.x * Y1.x + wn1.y * Y1.y;
        if (k0 == 0) {
            float r0 = ek[0].x * (Zk0.x + Zk0.y);
            *(float2*)&dst[0] = make_float2(r0, r1);
            dst[NH]        = ek[NH].x * (Zk0.x - Zk0.y);
            dst[NFULL - 1] = rm1;
        } else {
            float2 Zr0 = A2[swe(NH - k0)];
            float2 E0 = make_float2(0.5f * (Zk0.x + Zr0.x), 0.5f * (Zk0.y - Zr0.y));
            float2 O0 = make_float2(0.5f * (Zk0.y + Zr0.y), 0.5f * (Zr0.x - Zk0.x));
            float2 uu0 = sc(-(float)M_PI / 2048.0f * (float)k0);
            float2 Y0 = make_float2(E0.x + uu0.x * O0.x - uu0.y * O0.y,
                                    E0.y + uu0.x * O0.y + uu0.y * O0.x);
            float2 wk0 = ek[k0];
            float2 wn0 = ek[NFULL - k0];
            *(float2*)&dst[k0] = make_float2(wk0.x * Y0.x - wk0.y * Y0.y, r1);
            dst[NFULL - k0]     = wn0.x * Y0.x + wn0.y * Y0.y;
            dst[NFULL - k1]     = rm1;
        }
    }
}

// 32x32 LDS-tiled transpose
__global__ __launch_bounds__(256) void transpose4k(const float* __restrict__ in,
                                                   float* __restrict__ out) {
    __shared__ float tile[32][33];
    const int x0 = blockIdx.x * 32;
    const int y0 = blockIdx.y * 32;
    const int tx = threadIdx.x & 31;
    const int ty = threadIdx.x >> 5;

    #pragma unroll
    for (int i = 0; i < 32; i += 8)
        tile[ty + i][tx] = in[(size_t)(y0 + ty + i) * NFULL + (x0 + tx)];
    __syncthreads();
    #pragma unroll
    for (int i = 0; i < 32; i += 8)
        out[(size_t)(x0 + ty + i) * NFULL + (y0 + tx)] = tile[tx][ty + i];
}

extern "C" void kernel_launch(void* const* d_in, const int* in_sizes, int n_in,
                              void* d_out, int out_size, void* d_ws, size_t ws_size,
                              hipStream_t stream) {
    const float* x     = (const float*)d_in[0];
    const float* expkM = (const float*)d_in[1];
    const float* expkN = (const float*)d_in[2];
    float* out = (float*)d_out;
    float* ws1 = (float*)d_ws;

    dct_rows_b128<<<NFULL / 2, T, 0, stream>>>(x, expkN, ws1);
    transpose4k<<<dim3(128, 128), 256, 0, stream>>>(ws1, out);
    dct_rows_b128<<<NFULL / 2, T, 0, stream>>>(out, expkM, ws1);
    transpose4k<<<dim3(128, 128), 256, 0, stream>>>(ws1, out);
}